// Round 10
// baseline (204.184 us; speedup 1.0000x reference)
//
#include <hip/hip_runtime.h>
#include <hip/hip_bf16.h>

// Shapes: B=4, LQ=LKV=1024, D=1024, H=16, HD=64, N=H*HD=1024, M=B*LQ=4096
// Inputs  (f32): queries[4,1024,1024], context[4,1024,1024],
//   Wq/Wk/Wv[16,1024,64], bq/bk/bv[16,64], Wo[1024,1024], bo[1024]
// Outputs (f32, concat): out[4,1024,1024], residual[4,1024,1024]
// ws (u16, 56 MB): Aq 4M | Ac 4M | Wqt 1M | Wkt 1M | Wvt 1M | Wot 1M |
//                  qws 4M (x0.125) | kws 4M | vtws 4M (dim-major) | mws 4M

typedef unsigned short u16;
typedef unsigned int u32;
typedef __attribute__((ext_vector_type(8))) short short8;   // 8 bf16 = 4 VGPRs
typedef __attribute__((ext_vector_type(4))) float f32x4;

__device__ __forceinline__ float bf2f(u16 u) {
    union { u32 i; float f; } cv;
    cv.i = ((u32)u) << 16;
    return cv.f;
}

__device__ __forceinline__ u16 f2bf(float f) {
    u32 x = __float_as_uint(f);
    u32 r = (x + 0x7fffu + ((x >> 16) & 1u)) >> 16;  // RNE
    return (u16)r;
}

// async global->LDS, 16B/lane; lds base MUST be wave-uniform (HW adds lane*16)
__device__ __forceinline__ void glds16(u16* lds, const u16* g) {
    __builtin_amdgcn_global_load_lds(
        (const __attribute__((address_space(1))) void*)g,
        (__attribute__((address_space(3))) void*)lds, 16, 0, 0);
}

// ---------------------------------------------------------------------------
// Fused pre-pass, flat grid 5120 blocks x 256 thr (unchanged)
// ---------------------------------------------------------------------------
__global__ __launch_bounds__(256) void prep(
    const float* __restrict__ q, const float* __restrict__ ctx,
    const float* __restrict__ Wq, const float* __restrict__ Wk,
    const float* __restrict__ Wv, const float* __restrict__ Wo,
    u16* __restrict__ Aq, u16* __restrict__ Ac,
    u16* __restrict__ Wqt, u16* __restrict__ Wkt,
    u16* __restrict__ Wvt, u16* __restrict__ Wot)
{
    __shared__ float ls[64][65];
    const int t = threadIdx.x;
    int bid = blockIdx.x;

    if (bid < 4096) {
        const float* in = (bid < 2048) ? q : ctx;
        u16* out = (bid < 2048) ? Aq : Ac;
        size_t i = ((size_t)(bid & 2047) * 256 + t) * 8;
        float4 v0 = *(const float4*)(in + i);
        float4 v1 = *(const float4*)(in + i + 4);
        short8 p;
        p[0] = (short)f2bf(v0.x); p[1] = (short)f2bf(v0.y);
        p[2] = (short)f2bf(v0.z); p[3] = (short)f2bf(v0.w);
        p[4] = (short)f2bf(v1.x); p[5] = (short)f2bf(v1.y);
        p[6] = (short)f2bf(v1.z); p[7] = (short)f2bf(v1.w);
        *(short8*)(out + i) = p;
        return;
    }
    bid -= 4096;
    const float* in; u16* out; int C; size_t moff; int rt, ct;
    if (bid < 768) {
        const int m = bid >> 8, idx = bid & 255;
        in = (m == 0) ? Wq : (m == 1) ? Wk : Wv;
        out = (m == 0) ? Wqt : (m == 1) ? Wkt : Wvt;
        C = 64; rt = (idx & 15) * 64; ct = 0; moff = (size_t)(idx >> 4) * 65536;
    } else {
        const int idx = bid - 768;
        in = Wo; out = Wot; C = 1024; moff = 0;
        rt = (idx & 15) * 64; ct = (idx >> 4) * 64;
    }
    #pragma unroll
    for (int i = 0; i < 4; ++i) {
        int s = i * 256 + t;
        int row = s >> 4, chunk = s & 15;
        float4 v = *(const float4*)(in + moff + (size_t)(rt + row) * C + ct + chunk * 4);
        ls[row][chunk * 4 + 0] = v.x;
        ls[row][chunk * 4 + 1] = v.y;
        ls[row][chunk * 4 + 2] = v.z;
        ls[row][chunk * 4 + 3] = v.w;
    }
    __syncthreads();
    #pragma unroll
    for (int i = 0; i < 2; ++i) {
        int s = i * 256 + t;
        int n = s >> 3, kc = s & 7;
        short8 p;
        #pragma unroll
        for (int j = 0; j < 8; ++j) p[j] = (short)f2bf(ls[kc * 8 + j][n]);
        *(short8*)(out + moff + (size_t)(ct + n) * 1024 + rt + kc * 8) = p;
    }
}

// ---------------------------------------------------------------------------
// m97-style MFMA GEMM core (round-6 version — best measured for qkv):
// 256 thr = 4 waves, BM=BN=128, BK=32, K=1024. LDS unpadded [128][32].
// ---------------------------------------------------------------------------
__device__ __forceinline__ void gemm_core(
    const u16* __restrict__ A, const u16* __restrict__ Wt,
    int m0, u16* As, u16* Bs, f32x4 (&acc)[4][4])
{
    const int t = threadIdx.x;                 // 0..255
    const int w = t >> 6, lane = t & 63;
    const int quad = lane >> 4, c = lane & 15;
    const int srow = w * 32 + (lane >> 2);     // staging row (of 128)
    const int sch = lane & 3;                  // 8-u16 chunk within 32

    const u16* gA = A + (size_t)(m0 + srow) * 1024 + sch * 8;
    const u16* gB = Wt + (size_t)srow * 1024 + sch * 8;
    u16* lA = As + w * 32 * 32;                // wave-uniform LDS base
    u16* lB = Bs + w * 32 * 32;
    const u16* afr = As + ((w >> 1) * 64 + c) * 32 + quad * 8;
    const u16* bfr = Bs + ((w & 1) * 64 + c) * 32 + quad * 8;

    for (int kt = 0; kt < 1024; kt += 32) {
        glds16(lA,           gA + kt);
        glds16(lA + 16 * 32, gA + kt + 16 * 1024);
        glds16(lB,           gB + kt);
        glds16(lB + 16 * 32, gB + kt + 16 * 1024);
        __syncthreads();
        short8 af[4], bf[4];
        #pragma unroll
        for (int rs = 0; rs < 4; ++rs) af[rs] = *(const short8*)(afr + rs * 16 * 32);
        #pragma unroll
        for (int cs = 0; cs < 4; ++cs) bf[cs] = *(const short8*)(bfr + cs * 16 * 32);
        #pragma unroll
        for (int rs = 0; rs < 4; ++rs)
            #pragma unroll
            for (int cs = 0; cs < 4; ++cs)
                acc[rs][cs] = __builtin_amdgcn_mfma_f32_16x16x32_bf16(
                    af[rs], bf[cs], acc[rs][cs], 0, 0, 0);
        __syncthreads();
    }
}

// ---------------------------------------------------------------------------
// Fused Q/K/V projection (round-6 version, 43.9 us measured).
// grid (8 ntiles, 32 mtiles, 3 = q/k/v), 256 thr.
// ---------------------------------------------------------------------------
__global__ __launch_bounds__(256, 3) void gemm_qkv(
    const u16* __restrict__ Aq, const u16* __restrict__ Ac,
    const u16* __restrict__ Wqt, const u16* __restrict__ Wkt,
    const u16* __restrict__ Wvt,
    const float* __restrict__ bq, const float* __restrict__ bk,
    const float* __restrict__ bv,
    u16* __restrict__ qws, u16* __restrict__ kws, u16* __restrict__ vtws,
    float* __restrict__ resid)
{
    __shared__ u16 As[128 * 32];
    __shared__ u16 Bs[128 * 32];
    const int n0 = blockIdx.x * 128, m0 = blockIdx.y * 128, z = blockIdx.z;
    const int t = threadIdx.x;
    const int w = t >> 6, lane = t & 63;
    const int quad = lane >> 4, c = lane & 15;

    const u16* A = (z == 0) ? Aq : Ac;
    const u16* Wt = ((z == 0) ? Wqt : (z == 1) ? Wkt : Wvt) + (size_t)n0 * 1024;
    const float* bias = (z == 0) ? bq : (z == 1) ? bk : bv;

    f32x4 acc[4][4] = {};
    gemm_core(A, Wt, m0, As, Bs, acc);

    const int h = blockIdx.x * 2 + (w & 1);
    float bb[4];
    #pragma unroll
    for (int cs = 0; cs < 4; ++cs) bb[cs] = bias[h * 64 + cs * 16 + c];

    if (z == 2) {
        #pragma unroll
        for (int rs = 0; rs < 4; ++rs) {
            const int l0 = m0 + (w >> 1) * 64 + rs * 16 + quad * 4;
            const int b = l0 >> 10, l = l0 & 1023;
            #pragma unroll
            for (int cs = 0; cs < 4; ++cs) {
                const int hd = cs * 16 + c;
                ushort4 pk;
                pk.x = f2bf(acc[rs][cs][0] + bb[cs]);
                pk.y = f2bf(acc[rs][cs][1] + bb[cs]);
                pk.z = f2bf(acc[rs][cs][2] + bb[cs]);
                pk.w = f2bf(acc[rs][cs][3] + bb[cs]);
                *(ushort4*)(vtws + ((size_t)(b * 16 + h) * 64 + hd) * 1024 + l) = pk;
            }
        }
    } else {
        u16* dst = (z == 0) ? qws : kws;
        const float scale = (z == 0) ? 0.125f : 1.0f;
        #pragma unroll
        for (int rs = 0; rs < 4; ++rs) {
            #pragma unroll
            for (int r = 0; r < 4; ++r) {
                const int row = m0 + (w >> 1) * 64 + rs * 16 + quad * 4 + r;
                const int b = row >> 10, l = row & 1023;
                u16* drow = dst + (((size_t)(b * 16 + h) * 1024) + l) * 64;
                float* rrow = (z == 0) ? (resid + (size_t)row * 1024 + h * 64) : nullptr;
                #pragma unroll
                for (int cs = 0; cs < 4; ++cs) {
                    float v = acc[rs][cs][r] + bb[cs];
                    drow[cs * 16 + c] = f2bf(v * scale);
                    if (z == 0) rrow[cs * 16 + c] = v;
                }
            }
        }
    }
}

// ---------------------------------------------------------------------------
// Output projection v2 (round-7 version): 128m x 64n tiles, flat grid 512,
// XCD-aware swizzle, BK=32.
// ---------------------------------------------------------------------------
__global__ __launch_bounds__(256, 3) void gemm_out(
    const u16* __restrict__ A, const u16* __restrict__ Wot,
    const float* __restrict__ bo, float* __restrict__ out)
{
    __shared__ u16 As[128 * 32];   // 8 KB
    __shared__ u16 Bs[64 * 32];    // 4 KB
    const int f = blockIdx.x;
    const int xcd = f & 7, k = f >> 3;
    const int m0 = (xcd * 4 + (k & 3)) * 128;
    const int n0 = (k >> 2) * 64;
    const int t = threadIdx.x;
    const int w = t >> 6, lane = t & 63;
    const int quad = lane >> 4, c = lane & 15;

    const int arow = w * 32 + (lane >> 2), ach = lane & 3;
    const int brow = w * 16 + (lane >> 2);
    const u16* gA = A + (size_t)(m0 + arow) * 1024 + ach * 8;
    const u16* gB = Wot + (size_t)(n0 + brow) * 1024 + ach * 8;
    u16* lA = As + w * 32 * 32;
    u16* lB = Bs + w * 16 * 32;
    const u16* afr = As + ((w >> 1) * 64 + c) * 32 + quad * 8;
    const u16* bfr = Bs + ((w & 1) * 32 + c) * 32 + quad * 8;

    f32x4 acc[4][2] = {};
    for (int kt = 0; kt < 1024; kt += 32) {
        glds16(lA,           gA + kt);
        glds16(lA + 16 * 32, gA + kt + 16 * 1024);
        glds16(lB,           gB + kt);
        __syncthreads();
        short8 af[4], bf[2];
        #pragma unroll
        for (int rs = 0; rs < 4; ++rs) af[rs] = *(const short8*)(afr + rs * 16 * 32);
        #pragma unroll
        for (int cs = 0; cs < 2; ++cs) bf[cs] = *(const short8*)(bfr + cs * 16 * 32);
        #pragma unroll
        for (int rs = 0; rs < 4; ++rs)
            #pragma unroll
            for (int cs = 0; cs < 2; ++cs)
                acc[rs][cs] = __builtin_amdgcn_mfma_f32_16x16x32_bf16(
                    af[rs], bf[cs], acc[rs][cs], 0, 0, 0);
        __syncthreads();
    }

    const int nb = n0 + (w & 1) * 32;
    float bb[2];
    #pragma unroll
    for (int cs = 0; cs < 2; ++cs) bb[cs] = bo[nb + cs * 16 + c];

    #pragma unroll
    for (int rs = 0; rs < 4; ++rs) {
        #pragma unroll
        for (int r = 0; r < 4; ++r) {
            const int row = m0 + (w >> 1) * 64 + rs * 16 + quad * 4 + r;
            float* orow = out + (size_t)row * 1024 + nb;
            #pragma unroll
            for (int cs = 0; cs < 2; ++cs)
                orow[cs * 16 + c] = acc[rs][cs][r] + bb[cs];
        }
    }
}

// ---------------------------------------------------------------------------
// MFMA flash attention v6: BARRIER-FREE main loop via wave-private key-split.
// grid 1024 flat (XCD-grouped: xcd=f&7 owns 8 heads), 256 thr = 4 waves.
// Block = (b,h, 64 q-rows); wave w owns keys [w*256, w*256+256) in 8 tiles
// of 32 keys, staged into wave-private LDS via glds16 + manual
// s_waitcnt vmcnt(0) (no __syncthreads until the final cross-wave O/l
// reduction). Unshifted exp; P per wave in LDS (stride 36 u16 ->
// conflict-free write AND A-frag read). K tiles 128B rows + chunk^(c&7)
// swizzle (0-conflict, validated r9); V tiles 64B rows + chunk^((c>>1)&3).
// Epilogue: bf16 O exchange (reuses staging LDS) + lsum exchange.
// ---------------------------------------------------------------------------
__global__ __launch_bounds__(256, 2) void attn_mfma(
    const u16* __restrict__ qws, const u16* __restrict__ kws,
    const u16* __restrict__ vtws, u16* __restrict__ multi)
{
    __shared__ u16 smem[26112];        // 32KB staging | 9216 P | 512 lsum(f32)
    const int t = threadIdx.x;
    const int w = t >> 6, lane = t & 63;
    const int quad = lane >> 4, c = lane & 15;
    const int f = blockIdx.x;
    const int xcd = f & 7, j = f >> 3;
    const int bh = xcd * 8 + (j & 7);          // 8 heads per XCD
    const int qt = j >> 3;
    const int b = bh >> 4, h = bh & 15;
    const int q0 = qt * 64;

    const u16* qb = qws + ((size_t)bh * 1024 + q0) * 64;
    const u16* kb = kws + (size_t)bh * 65536;
    const u16* vb = vtws + (size_t)bh * 65536;

    // Q A-frags for ALL 64 q-rows: qa[mt][kh]: lane holds Q[q0+mt*16+c][kh*32+quad*8..]
    short8 qa[4][2];
    #pragma unroll
    for (int mt = 0; mt < 4; ++mt) {
        const u16* qr = qb + (size_t)(mt * 16 + c) * 64 + quad * 8;
        qa[mt][0] = *(const short8*)(qr);
        qa[mt][1] = *(const short8*)(qr + 32);
    }

    u16* stgK = smem + w * 4096;               // 32 keys x 64 dims (128B rows)
    u16* stgV = stgK + 2048;                   // 64 dims x 32 keys (64B rows)
    u16* pw   = smem + 16384 + w * 2304;       // P: 64 rows x stride 36
    float* lsumLDS = (float*)(smem + 25600);   // [4 waves][64 q]

    // staging lane->addr constants
    const int gkc = (lane & 7) ^ ((lane >> 3) & 7);      // K global chunk
    const int gvc = (lane & 3) ^ ((lane >> 3) & 3);      // V global chunk
    const int krow = lane >> 3;                          // 0..7 within call
    const int vdim = lane >> 2;                          // 0..15 within call

    f32x4 O[4][4] = {};                        // [mt][nt(d)] per-wave partials
    f32x4 lp[4] = {};                          // lsum partials [mt][r]
    const int kw = w * 256;
    const int cx = c & 7;
    const int vsw = quad ^ ((c >> 1) & 3);     // V frag phys chunk

    for (int i = 0; i < 8; ++i) {
        const int kt = kw + i * 32;
        // stage K (4 calls x 8 rows) and V (4 calls x 16 dims)
        #pragma unroll
        for (int jj = 0; jj < 4; ++jj)
            glds16(stgK + jj * 512, kb + (size_t)(kt + jj * 8 + krow) * 64 + gkc * 8);
        #pragma unroll
        for (int jj = 0; jj < 4; ++jj)
            glds16(stgV + jj * 512, vb + (size_t)(jj * 16 + vdim) * 1024 + kt + gvc * 8);
        __asm__ volatile("s_waitcnt vmcnt(0)" ::: "memory");

        // K B-frags (reused across mt): kf[nt][kh]
        short8 kf[2][2];
        #pragma unroll
        for (int nt = 0; nt < 2; ++nt)
            #pragma unroll
            for (int kh = 0; kh < 2; ++kh)
                kf[nt][kh] = *(const short8*)(stgK + (nt * 16 + c) * 64
                                              + (((kh * 4 + quad)) ^ cx) * 8);

        // S + exp + P-write per mt
        #pragma unroll
        for (int mt = 0; mt < 4; ++mt) {
            f32x4 s0 = {}, s1 = {};
            s0 = __builtin_amdgcn_mfma_f32_16x16x32_bf16(qa[mt][0], kf[0][0], s0, 0, 0, 0);
            s0 = __builtin_amdgcn_mfma_f32_16x16x32_bf16(qa[mt][1], kf[0][1], s0, 0, 0, 0);
            s1 = __builtin_amdgcn_mfma_f32_16x16x32_bf16(qa[mt][0], kf[1][0], s1, 0, 0, 0);
            s1 = __builtin_amdgcn_mfma_f32_16x16x32_bf16(qa[mt][1], kf[1][1], s1, 0, 0, 0);
            #pragma unroll
            for (int r = 0; r < 4; ++r) {
                float p0 = __expf(s0[r]);
                float p1 = __expf(s1[r]);
                lp[mt][r] += p0 + p1;
                const int prow = (mt * 16 + quad * 4 + r) * 36;
                pw[prow + c]      = (u16)(__float_as_uint(p0) >> 16);
                pw[prow + 16 + c] = (u16)(__float_as_uint(p1) >> 16);
            }
        }

        // V B-frags + PV
        short8 vf[4];
        #pragma unroll
        for (int nt = 0; nt < 4; ++nt)
            vf[nt] = *(const short8*)(stgV + (nt * 16 + c) * 32 + vsw * 8);
        #pragma unroll
        for (int mt = 0; mt < 4; ++mt) {
            short8 pa = *(const short8*)(pw + (mt * 16 + c) * 36 + quad * 8);
            #pragma unroll
            for (int nt = 0; nt < 4; ++nt)
                O[mt][nt] = __builtin_amdgcn_mfma_f32_16x16x32_bf16(
                    pa, vf[nt], O[mt][nt], 0, 0, 0);
        }
        // ensure all LDS reads retired before next tile's DMA overwrites
        __asm__ volatile("s_waitcnt lgkmcnt(0)" ::: "memory");
    }

    // ---- epilogue: cross-wave reduction ----
    __syncthreads();                           // everyone done with staging LDS

    // reduce lsum partials over the 16 c-lanes of each quad-group
    #pragma unroll
    for (int mt = 0; mt < 4; ++mt)
        #pragma unroll
        for (int r = 0; r < 4; ++r) {
            float v = lp[mt][r];
            v += __shfl_xor(v, 1);
            v += __shfl_xor(v, 2);
            v += __shfl_xor(v, 4);
            v += __shfl_xor(v, 8);
            lp[mt][r] = v;
        }
    if (c < 4) {
        #pragma unroll
        for (int mt = 0; mt < 4; ++mt)
            lsumLDS[w * 64 + mt * 16 + quad * 4 + c] = lp[mt][c];
    }

    // write O partials as packed bf16 pairs into the (reused) staging region
    u32* ex = (u32*)smem;
    #pragma unroll
    for (int mt = 0; mt < 4; ++mt)
        #pragma unroll
        for (int nt = 0; nt < 4; ++nt) {
            u32 lo = (u32)f2bf(O[mt][nt][0]) | ((u32)f2bf(O[mt][nt][1]) << 16);
            u32 hi = (u32)f2bf(O[mt][nt][2]) | ((u32)f2bf(O[mt][nt][3]) << 16);
            uint2 pk; pk.x = lo; pk.y = hi;
            *(uint2*)(ex + w * 2048 + (mt * 4 + nt) * 128 + lane * 2) = pk;
        }
    __syncthreads();

    // finalize: wave w owns q rows q0 + w*16 + quad*4 + r, dims nt*16+c
    float ls[4];
    #pragma unroll
    for (int r = 0; r < 4; ++r) {
        float s = 0.f;
        #pragma unroll
        for (int wp = 0; wp < 4; ++wp)
            s += lsumLDS[wp * 64 + w * 16 + quad * 4 + r];
        ls[r] = 1.0f / s;
    }

    float fo[4][4];                            // [nt][r]
    #pragma unroll
    for (int nt = 0; nt < 4; ++nt) {
        float a0 = 0.f, a1 = 0.f, a2 = 0.f, a3 = 0.f;
        #pragma unroll
        for (int wp = 0; wp < 4; ++wp) {
            uint2 pk = *(const uint2*)(ex + wp * 2048 + (w * 4 + nt) * 128 + lane * 2);
            a0 += bf2f((u16)(pk.x & 0xffff));
            a1 += bf2f((u16)(pk.x >> 16));
            a2 += bf2f((u16)(pk.y & 0xffff));
            a3 += bf2f((u16)(pk.y >> 16));
        }
        fo[nt][0] = a0; fo[nt][1] = a1; fo[nt][2] = a2; fo[nt][3] = a3;
    }

    u16* ob = multi + ((size_t)b * 1024 + q0 + w * 16 + quad * 4) * 1024 + h * 64 + c;
    #pragma unroll
    for (int r = 0; r < 4; ++r) {
        u16* orow = ob + (size_t)r * 1024;
        #pragma unroll
        for (int nt = 0; nt < 4; ++nt)
            orow[nt * 16] = f2bf(fo[nt][r] * ls[r]);
    }
}

extern "C" void kernel_launch(void* const* d_in, const int* in_sizes, int n_in,
                              void* d_out, int out_size, void* d_ws, size_t ws_size,
                              hipStream_t stream) {
    const float* queries = (const float*)d_in[0];
    const float* context = (const float*)d_in[1];
    const float* Wq = (const float*)d_in[2];
    const float* bq = (const float*)d_in[3];
    const float* Wk = (const float*)d_in[4];
    const float* bk = (const float*)d_in[5];
    const float* Wv = (const float*)d_in[6];
    const float* bv = (const float*)d_in[7];
    const float* Wo = (const float*)d_in[8];
    const float* bo = (const float*)d_in[9];

    float* out = (float*)d_out;                     // [4,1024,1024] f32
    float* resid = out + (size_t)4 * 1024 * 1024;   // [4,1024,1024] f32

    const size_t M1 = 1024 * 1024;
    u16* Aq   = (u16*)d_ws;          // 4M
    u16* Ac   = Aq + 4 * M1;         // 4M
    u16* Wqt  = Ac + 4 * M1;         // 1M
    u16* Wkt  = Wqt + M1;            // 1M
    u16* Wvt  = Wkt + M1;            // 1M
    u16* Wot  = Wvt + M1;            // 1M
    u16* qws  = Wot + M1;            // 4M (pre-scaled 0.125)
    u16* kws  = qws + 4 * M1;        // 4M
    u16* vtws = kws + 4 * M1;        // 4M [B,H,64,1024]
    u16* mws  = vtws + 4 * M1;       // 4M [B,1024,1024]

    prep<<<5120, 256, 0, stream>>>(queries, context, Wq, Wk, Wv, Wo,
                                   Aq, Ac, Wqt, Wkt, Wvt, Wot);
    gemm_qkv<<<dim3(8, 32, 3), 256, 0, stream>>>(Aq, Ac, Wqt, Wkt, Wvt,
                                                 bq, bk, bv, qws, kws, vtws, resid);
    attn_mfma<<<1024, 256, 0, stream>>>(qws, kws, vtws, mws);
    gemm_out<<<512, 256, 0, stream>>>(mws, Wot, bo, out);
}